// Round 1
// baseline (242.408 us; speedup 1.0000x reference)
//
#include <hip/hip_runtime.h>

// GuidedFilterLayer: out = ((x+1)/2)*(1-eps) + eps*boxblur15(g + offset), remapped to [-1,1]
//   g      = luma((x+1)/2), per-pixel
//   offset = mean(inputs) - mean(g)   (global scalars)
//   final algebra: out = x*(1-eps) + eps*(2*smoothed - 1)
// Shapes fixed by the reference: x [16,512,512,3] fp32 NHWC.

#define BATCH  16
#define HEIGHT 512
#define WIDTH  512
#define NPIX   (BATCH * HEIGHT * WIDTH)   // 4,194,304
#define RAD    7
#define KS     15
#define EPSV   0.01f

// ---------------- K1: luma + global sums ----------------
// 4 pixels / thread via 3 float4 loads (12 floats = 4 RGB pixels).
__global__ __launch_bounds__(256) void k_luma_reduce(const float* __restrict__ x,
                                                     float* __restrict__ g,
                                                     float* __restrict__ sums) {
    int idx = blockIdx.x * 256 + threadIdx.x;      // grid sized exactly NPIX/4
    const float4* xv = (const float4*)x;
    float4 a = xv[(size_t)idx * 3 + 0];
    float4 b = xv[(size_t)idx * 3 + 1];
    float4 c = xv[(size_t)idx * 3 + 2];
    float vals[12] = {a.x, a.y, a.z, a.w, b.x, b.y, b.z, b.w, c.x, c.y, c.z, c.w};

    float sG = 0.f, sI = 0.f;
    float lum[4];
#pragma unroll
    for (int i = 0; i < 4; i++) {
        float r  = (vals[3 * i + 0] + 1.f) * 0.5f;
        float gg = (vals[3 * i + 1] + 1.f) * 0.5f;
        float bb = (vals[3 * i + 2] + 1.f) * 0.5f;
        float l  = 0.2989f * r + 0.5870f * gg + 0.1140f * bb;
        lum[i] = l;
        sG += l;
        sI += r + gg + bb;
    }
    float4 gv = make_float4(lum[0], lum[1], lum[2], lum[3]);
    ((float4*)g)[idx] = gv;

    // wave64 reduce
#pragma unroll
    for (int off = 32; off > 0; off >>= 1) {
        sG += __shfl_down(sG, off, 64);
        sI += __shfl_down(sI, off, 64);
    }
    __shared__ float redG[4], redI[4];
    int lane = threadIdx.x & 63;
    int wave = threadIdx.x >> 6;
    if (lane == 0) { redG[wave] = sG; redI[wave] = sI; }
    __syncthreads();
    if (threadIdx.x == 0) {
        atomicAdd(&sums[0], redG[0] + redG[1] + redG[2] + redG[3]);
        atomicAdd(&sums[1], redI[0] + redI[1] + redI[2] + redI[3]);
    }
}

// ---------------- K2: horizontal 15-tap (zero pad), offset added pre-blur ----------------
__global__ __launch_bounds__(256) void k_hblur(const float* __restrict__ g,
                                               float* __restrict__ tmp,
                                               const float* __restrict__ sums) {
    int seg = blockIdx.x;
    int row = seg >> 1;               // 2 segments of 256 per 512-wide row
    int x0  = (seg & 1) << 8;
    __shared__ float s[256 + 2 * RAD];

    float meanG  = sums[0] * (1.f / (float)NPIX);
    float meanI  = sums[1] * (1.f / (3.f * (float)NPIX));
    float offset = meanI - meanG;

    const float* grow = g + (size_t)row * WIDTH;
    int tx = threadIdx.x;
    for (int i = tx; i < 256 + 2 * RAD; i += 256) {
        int xx = x0 - RAD + i;
        s[i] = (xx >= 0 && xx < WIDTH) ? (grow[xx] + offset) : 0.f;
    }
    __syncthreads();

    float sum = 0.f;
#pragma unroll
    for (int d = 0; d < KS; d++) sum += s[tx + d];
    tmp[(size_t)row * WIDTH + x0 + tx] = sum;      // normalization (1/225) folded into K3
}

// ---------------- K3: vertical 15-tap (zero pad per image) + fused combine ----------------
__global__ __launch_bounds__(256) void k_vblur_combine(const float* __restrict__ tmp,
                                                       const float* __restrict__ x,
                                                       float* __restrict__ out) {
    int p      = blockIdx.x * 256 + threadIdx.x;   // pixel index, grid = NPIX/256
    int xx     = p & (WIDTH - 1);
    int rowIdx = p >> 9;                            // /WIDTH
    int y      = rowIdx & (HEIGHT - 1);
    int b      = rowIdx >> 9;                       // /HEIGHT

    const float* base = tmp + ((size_t)b * HEIGHT) * WIDTH + xx;
    float sum = 0.f;
#pragma unroll
    for (int d = -RAD; d <= RAD; d++) {
        int yy = y + d;
        if (yy >= 0 && yy < HEIGHT) sum += base[(size_t)yy * WIDTH];
    }
    float sm    = sum * (1.f / (float)(KS * KS));
    float addv  = EPSV * (2.f * sm - 1.f);
    const float scale = 1.f - EPSV;

    size_t o = (size_t)p * 3;
    out[o + 0] = x[o + 0] * scale + addv;
    out[o + 1] = x[o + 1] * scale + addv;
    out[o + 2] = x[o + 2] * scale + addv;
}

extern "C" void kernel_launch(void* const* d_in, const int* in_sizes, int n_in,
                              void* d_out, int out_size, void* d_ws, size_t ws_size,
                              hipStream_t stream) {
    const float* x   = (const float*)d_in[0];
    float*       out = (float*)d_out;

    // ws layout: [0,256): sums (2 floats used) | g: NPIX floats | tmp: NPIX floats
    float* sums = (float*)d_ws;
    float* g    = (float*)((char*)d_ws + 256);
    float* tmp  = g + NPIX;

    hipMemsetAsync(d_ws, 0, 256, stream);  // zero the atomic accumulators (ws is poisoned 0xAA)

    k_luma_reduce<<<NPIX / 4 / 256, 256, 0, stream>>>(x, g, sums);
    k_hblur<<<BATCH * HEIGHT * (WIDTH / 256), 256, 0, stream>>>(g, tmp, sums);
    k_vblur_combine<<<NPIX / 256, 256, 0, stream>>>(tmp, x, out);
}

// Round 3
// 231.884 us; speedup vs baseline: 1.0454x; 1.0454x over previous
//
#include <hip/hip_runtime.h>

// GuidedFilterLayer: out = x*(1-eps) + eps*(2*boxblur15(g + offset) - 1)
//   g      = luma((x+1)/2), per-pixel
//   offset = mean(inputs) - mean(g)   (global scalars, applied pre-blur since
//            zero-padding makes the blur non-linear in the constant at borders)
// Shapes fixed by the reference: x [16,512,512,3] fp32 NHWC.

#define BATCH  16
#define HEIGHT 512
#define WIDTH  512
#define NPIX   (BATCH * HEIGHT * WIDTH)   // 4,194,304
#define RAD    7
#define KS     15
#define EPSV   0.01f

#define W_R 0.2989f
#define W_G 0.5870f
#define W_B 0.1140f

// ---------------- K1: luma + global sums ----------------
// Block = 1024 pixels = 3072 floats = 768 float4. Coalesced float4 loads into
// LDS, then per-thread pixel math with NAMED SCALARS ONLY (R0 post-mortem:
// local arrays -> scratch, VGPR=16, 110us).
__global__ __launch_bounds__(256) void k_luma_reduce(const float* __restrict__ x,
                                                     float* __restrict__ g,
                                                     float* __restrict__ sums) {
    __shared__ float s[3072];
    int t = threadIdx.x;
    size_t base4 = (size_t)blockIdx.x * 768;       // float4 units
    const float4* xv = (const float4*)x;
    float4* s4 = (float4*)s;
#pragma unroll
    for (int i = 0; i < 3; i++)
        s4[i * 256 + t] = xv[base4 + i * 256 + t];
    __syncthreads();

    const float* sp = s + t * 12;
    float r0 = (sp[0]  + 1.f) * 0.5f, g0 = (sp[1]  + 1.f) * 0.5f, b0 = (sp[2]  + 1.f) * 0.5f;
    float r1 = (sp[3]  + 1.f) * 0.5f, g1 = (sp[4]  + 1.f) * 0.5f, b1 = (sp[5]  + 1.f) * 0.5f;
    float r2 = (sp[6]  + 1.f) * 0.5f, g2 = (sp[7]  + 1.f) * 0.5f, b2 = (sp[8]  + 1.f) * 0.5f;
    float r3 = (sp[9]  + 1.f) * 0.5f, g3 = (sp[10] + 1.f) * 0.5f, b3 = (sp[11] + 1.f) * 0.5f;

    float l0 = W_R * r0 + W_G * g0 + W_B * b0;
    float l1 = W_R * r1 + W_G * g1 + W_B * b1;
    float l2 = W_R * r2 + W_G * g2 + W_B * b2;
    float l3 = W_R * r3 + W_G * g3 + W_B * b3;

    ((float4*)g)[base4 / 3 + t] = make_float4(l0, l1, l2, l3);

    float sG = l0 + l1 + l2 + l3;
    float sI = r0 + g0 + b0 + r1 + g1 + b1 + r2 + g2 + b2 + r3 + g3 + b3;

#pragma unroll
    for (int off = 32; off > 0; off >>= 1) {
        sG += __shfl_down(sG, off, 64);
        sI += __shfl_down(sI, off, 64);
    }
    __shared__ float redG[4], redI[4];
    int lane = t & 63, wave = t >> 6;
    if (lane == 0) { redG[wave] = sG; redI[wave] = sI; }
    __syncthreads();
    if (t == 0) {
        atomicAdd(&sums[0], redG[0] + redG[1] + redG[2] + redG[3]);
        atomicAdd(&sums[1], redI[0] + redI[1] + redI[2] + redI[3]);
    }
}

// ---------------- K2: horizontal 15-tap (zero pad), offset added pre-blur ----------------
__global__ __launch_bounds__(256) void k_hblur(const float* __restrict__ g,
                                               float* __restrict__ tmp,
                                               const float* __restrict__ sums) {
    int seg = blockIdx.x;
    int row = seg >> 1;               // 2 segments of 256 per 512-wide row
    int x0  = (seg & 1) << 8;
    __shared__ float s[256 + 2 * RAD];

    float meanG  = sums[0] * (1.f / (float)NPIX);
    float meanI  = sums[1] * (1.f / (3.f * (float)NPIX));
    float offset = meanI - meanG;

    const float* grow = g + (size_t)row * WIDTH;
    int tx = threadIdx.x;
    for (int i = tx; i < 256 + 2 * RAD; i += 256) {
        int xx = x0 - RAD + i;
        s[i] = (xx >= 0 && xx < WIDTH) ? (grow[xx] + offset) : 0.f;
    }
    __syncthreads();

    float sum = 0.f;
#pragma unroll
    for (int d = 0; d < KS; d++) sum += s[tx + d];
    tmp[(size_t)row * WIDTH + x0 + tx] = sum;      // 1/225 folded into K3
}

// ---------------- K3: vertical 15-tap + fused combine, fully coalesced ----------------
// Block = 2 full rows (1024 pixels). Phase 1: each thread does the vertical
// blur for 4 x-adjacent pixels via 15 float4 taps (coalesced; tmp is 16.8 MB,
// 15x reuse served by L2/L3), stashes eps*(2*sm-1) in LDS. Phase 2: stream
// x -> out as 3 coalesced float4 per thread, addv gathered from LDS.
__global__ __launch_bounds__(256) void k_vblur_combine(const float* __restrict__ tmp,
                                                       const float* __restrict__ x,
                                                       float* __restrict__ out) {
    __shared__ float sAdd[1024];
    int t = threadIdx.x;
    int R = blockIdx.x * 2;                 // global row index of first row
    int b = R >> 9;                         // image index
    int y = R & (HEIGHT - 1);               // row-pair never straddles images
    int lr  = t >> 7;                       // local row 0/1  (4t/512)
    int col = (t << 2) & (WIDTH - 1);       // 4t % 512
    int yy0 = y + lr;

    const float* base = tmp + (((size_t)b * HEIGHT) * WIDTH) + col;
    float s0 = 0.f, s1 = 0.f, s2 = 0.f, s3 = 0.f;
#pragma unroll
    for (int d = -RAD; d <= RAD; d++) {
        int yy = yy0 + d;
        if (yy >= 0 && yy < HEIGHT) {
            float4 v = *(const float4*)(base + (size_t)yy * WIDTH);
            s0 += v.x; s1 += v.y; s2 += v.z; s3 += v.w;
        }
    }
    const float nrm = 1.f / (float)(KS * KS);
    int lp = t << 2;                         // local pixel index
    sAdd[lp + 0] = EPSV * (2.f * s0 * nrm - 1.f);
    sAdd[lp + 1] = EPSV * (2.f * s1 * nrm - 1.f);
    sAdd[lp + 2] = EPSV * (2.f * s2 * nrm - 1.f);
    sAdd[lp + 3] = EPSV * (2.f * s3 * nrm - 1.f);
    __syncthreads();

    const float scale = 1.f - EPSV;
    size_t base4 = (size_t)blockIdx.x * 768;     // float4 units into x/out
    const float4* xv = (const float4*)x;
    float4*       ov = (float4*)out;
#pragma unroll
    for (int i = 0; i < 3; i++) {
        int q = i * 256 + t;                 // local float4 index (floats 4q..4q+3)
        float4 xi = xv[base4 + q];
        float4 o;
        o.x = xi.x * scale + sAdd[(4 * q + 0) / 3];
        o.y = xi.y * scale + sAdd[(4 * q + 1) / 3];
        o.z = xi.z * scale + sAdd[(4 * q + 2) / 3];
        o.w = xi.w * scale + sAdd[(4 * q + 3) / 3];
        ov[base4 + q] = o;
    }
}

extern "C" void kernel_launch(void* const* d_in, const int* in_sizes, int n_in,
                              void* d_out, int out_size, void* d_ws, size_t ws_size,
                              hipStream_t stream) {
    const float* x   = (const float*)d_in[0];
    float*       out = (float*)d_out;

    // ws layout: [0,256): sums (2 floats used) | g: NPIX floats | tmp: NPIX floats
    float* sums = (float*)d_ws;
    float* g    = (float*)((char*)d_ws + 256);
    float* tmp  = g + NPIX;

    hipMemsetAsync(d_ws, 0, 256, stream);   // zero the atomic accumulators

    k_luma_reduce<<<NPIX / 1024, 256, 0, stream>>>(x, g, sums);
    k_hblur<<<BATCH * HEIGHT * (WIDTH / 256), 256, 0, stream>>>(g, tmp, sums);
    k_vblur_combine<<<NPIX / 1024, 256, 0, stream>>>(tmp, x, out);
}

// Round 6
// 128.051 us; speedup vs baseline: 1.8931x; 1.8109x over previous
//
#include <hip/hip_runtime.h>

// GuidedFilterLayer: out = x*(1-eps) + eps*(2*smoothed - 1)
//   g        = luma((x+1)/2)
//   smoothed = boxblur15_zeropad(g + offset)  with offset = mean(inputs)-mean(g)
// Linearity trick: boxblur_zeropad(g + c) = boxblur_zeropad(g) + c*cnt(x,y)/225,
// cnt(x,y) = cx(x)*cy(y), cx = #valid taps in x (closed form). So offset is only
// needed in the FINAL kernel -> luma+hblur fuse, no g intermediate, and the
// global reduction runs concurrently (no same-address atomics — R3 post-mortem:
// 8192 contended device atomics were the fixed 110us serializer).
// Shapes fixed by the reference: x [16,512,512,3] fp32 NHWC.

#define BATCH  16
#define HEIGHT 512
#define WIDTH  512
#define NPIX   (BATCH * HEIGHT * WIDTH)   // 4,194,304
#define RAD    7
#define KS     15
#define EPSV   0.01f

#define W_R 0.2989f
#define W_G 0.5870f
#define W_B 0.1140f

// ---------------- K1: fused luma + horizontal 15-tap + per-block partial sums ---------
// Block = 2 full rows (1024 px). x rows -> LDS (coalesced float4), luma into a
// zero-padded LDS row buffer, 15-tap hblur from LDS (stride-1 reads = conflict
// free), per-block sums to partials[bid] (NO contended atomics).
__global__ __launch_bounds__(256) void k_luma_hblur(const float* __restrict__ x,
                                                    float* __restrict__ tmp,
                                                    float2* __restrict__ partials) {
    __shared__ float sx[3072];
    __shared__ float sl[2][528];            // 7 zero pad each side: [0,7) g [7,519) pad [519,526)
    __shared__ float redG[4], redI[4];
    int t = threadIdx.x;

    if (t < 7) {                            // zero the halo pads once
        sl[0][t] = 0.f; sl[1][t] = 0.f;
        sl[0][519 + t] = 0.f; sl[1][519 + t] = 0.f;
    }

    size_t base4 = (size_t)blockIdx.x * 768;        // float4 units into x
    const float4* xv = (const float4*)x;
    float4* s4 = (float4*)sx;
#pragma unroll
    for (int i = 0; i < 3; i++)
        s4[i * 256 + t] = xv[base4 + i * 256 + t];
    __syncthreads();

    // luma for pixels p = t + 256*i  (lanes stride 3 floats in LDS -> 2-way = free)
    float sG = 0.f, sI = 0.f;
#pragma unroll
    for (int i = 0; i < 4; i++) {
        int p  = t + (i << 8);
        int lr = p >> 9;
        int c  = p & (WIDTH - 1);
        float r  = (sx[3 * p + 0] + 1.f) * 0.5f;
        float gg = (sx[3 * p + 1] + 1.f) * 0.5f;
        float bb = (sx[3 * p + 2] + 1.f) * 0.5f;
        float l  = W_R * r + W_G * gg + W_B * bb;
        sl[lr][RAD + c] = l;
        sG += l;
        sI += r + gg + bb;
    }

    // wave64 shuffle reduction (no LDS dependency until after the barrier)
#pragma unroll
    for (int off = 32; off > 0; off >>= 1) {
        sG += __shfl_down(sG, off, 64);
        sI += __shfl_down(sI, off, 64);
    }
    int lane = t & 63, wave = t >> 6;
    if (lane == 0) { redG[wave] = sG; redI[wave] = sI; }
    __syncthreads();                        // covers sl + redG/redI

    if (t == 0)
        partials[blockIdx.x] = make_float2(redG[0] + redG[1] + redG[2] + redG[3],
                                           redI[0] + redI[1] + redI[2] + redI[3]);

    // hblur: 15 unconditional LDS taps per pixel (padded), coalesced dword stores
    int row_g = blockIdx.x * 2;
#pragma unroll
    for (int i = 0; i < 4; i++) {
        int p  = t + (i << 8);
        int lr = p >> 9;
        int c  = p & (WIDTH - 1);
        float sum = 0.f;
#pragma unroll
        for (int d = 0; d < KS; d++) sum += sl[lr][c + d];
        tmp[(size_t)(row_g + lr) * WIDTH + c] = sum;   // 1/225 folded into K2
    }
}

// ---------------- K1.5: reduce 4096 partials -> offset (1 block, ~3us) ----------------
__global__ __launch_bounds__(256) void k_reduce(const float2* __restrict__ partials,
                                                float* __restrict__ sums) {
    int t = threadIdx.x;
    float sG = 0.f, sI = 0.f;
    for (int i = t; i < 4096; i += 256) {
        float2 v = partials[i];
        sG += v.x; sI += v.y;
    }
#pragma unroll
    for (int off = 32; off > 0; off >>= 1) {
        sG += __shfl_down(sG, off, 64);
        sI += __shfl_down(sI, off, 64);
    }
    __shared__ float rG[4], rI[4];
    int lane = t & 63, wave = t >> 6;
    if (lane == 0) { rG[wave] = sG; rI[wave] = sI; }
    __syncthreads();
    if (t == 0) {
        float SG = rG[0] + rG[1] + rG[2] + rG[3];
        float SI = rI[0] + rI[1] + rI[2] + rI[3];
        float meanG = SG * (1.f / (float)NPIX);
        float meanI = SI * (1.f / (3.f * (float)NPIX));
        sums[0] = meanI - meanG;            // the offset, directly
    }
}

// ---------------- K2: vertical 15-tap + closed-form border offset + fused combine -----
// Block = 2 full rows. Phase 1: vertical blur of 4 x-adjacent pixels via 15
// coalesced float4 taps (tmp reuse served by L2/L3), add offset*cx*cy/225,
// stash eps*(2*sm-1) in LDS. Phase 2: stream x -> out as coalesced float4.
__global__ __launch_bounds__(256) void k_vblur_combine(const float* __restrict__ tmp,
                                                       const float* __restrict__ x,
                                                       float* __restrict__ out,
                                                       const float* __restrict__ sums) {
    __shared__ float sAdd[1024];
    int t = threadIdx.x;
    int R = blockIdx.x * 2;
    int b = R >> 9;
    int y = R & (HEIGHT - 1);
    int lr  = t >> 7;
    int col = (t << 2) & (WIDTH - 1);
    int yy0 = y + lr;
    float offset = sums[0];

    const float* base = tmp + ((size_t)b * HEIGHT) * WIDTH + col;
    float s0 = 0.f, s1 = 0.f, s2 = 0.f, s3 = 0.f;
#pragma unroll
    for (int d = -RAD; d <= RAD; d++) {
        int yy = yy0 + d;
        if (yy >= 0 && yy < HEIGHT) {
            float4 v = *(const float4*)(base + (size_t)yy * WIDTH);
            s0 += v.x; s1 += v.y; s2 += v.z; s3 += v.w;
        }
    }
    const float nrm = 1.f / (float)(KS * KS);
    float cy = (float)(min(yy0, RAD) + 1 + min(HEIGHT - 1 - yy0, RAD));
    float c0 = (float)(min(col + 0, RAD) + 1 + min(WIDTH - 1 - col, RAD));
    float c1 = (float)(min(col + 1, RAD) + 1 + min(WIDTH - 2 - col, RAD));
    float c2 = (float)(min(col + 2, RAD) + 1 + min(WIDTH - 3 - col, RAD));
    float c3 = (float)(min(col + 3, RAD) + 1 + min(WIDTH - 4 - col, RAD));
    int lp = t << 2;
    sAdd[lp + 0] = EPSV * (2.f * (s0 + offset * c0 * cy) * nrm - 1.f);
    sAdd[lp + 1] = EPSV * (2.f * (s1 + offset * c1 * cy) * nrm - 1.f);
    sAdd[lp + 2] = EPSV * (2.f * (s2 + offset * c2 * cy) * nrm - 1.f);
    sAdd[lp + 3] = EPSV * (2.f * (s3 + offset * c3 * cy) * nrm - 1.f);
    __syncthreads();

    const float scale = 1.f - EPSV;
    size_t base4 = (size_t)blockIdx.x * 768;
    const float4* xv = (const float4*)x;
    float4*       ov = (float4*)out;
#pragma unroll
    for (int i = 0; i < 3; i++) {
        int q = i * 256 + t;
        float4 xi = xv[base4 + q];
        float4 o;
        o.x = xi.x * scale + sAdd[(4 * q + 0) / 3];
        o.y = xi.y * scale + sAdd[(4 * q + 1) / 3];
        o.z = xi.z * scale + sAdd[(4 * q + 2) / 3];
        o.w = xi.w * scale + sAdd[(4 * q + 3) / 3];
        ov[base4 + q] = o;
    }
}

extern "C" void kernel_launch(void* const* d_in, const int* in_sizes, int n_in,
                              void* d_out, int out_size, void* d_ws, size_t ws_size,
                              hipStream_t stream) {
    const float* x   = (const float*)d_in[0];
    float*       out = (float*)d_out;

    // ws layout: [0,256): sums | [256, 256+32K): partials (4096 float2) | tmp: NPIX floats
    float*  sums     = (float*)d_ws;
    float2* partials = (float2*)((char*)d_ws + 256);
    float*  tmp      = (float*)((char*)d_ws + 256 + 4096 * sizeof(float2));

    const int NBLK = BATCH * HEIGHT / 2;    // 4096

    k_luma_hblur<<<NBLK, 256, 0, stream>>>(x, tmp, partials);
    k_reduce<<<1, 256, 0, stream>>>(partials, sums);
    k_vblur_combine<<<NBLK, 256, 0, stream>>>(tmp, x, out, sums);
}

// Round 7
// 119.104 us; speedup vs baseline: 2.0353x; 1.0751x over previous
//
#include <hip/hip_runtime.h>

// GuidedFilterLayer: out = x*(1-eps) + eps*(2*smoothed - 1)
//   g        = luma((x+1)/2)
//   smoothed = boxblur15_zeropad(g + offset),  offset = mean(inputs)-mean(g)
// Linearity: boxblur_zeropad(g + c) = boxblur_zeropad(g) + c*cx(x)*cy(y)/225
// (closed-form border tap counts), so the offset is only needed in the final
// combine -> luma+hblur fuse with no g intermediate, reduction has no
// contended atomics (R3 post-mortem: 8192 same-address device atomics were a
// fixed ~110us serializer; removing them was 232->128us).
// R6 post-mortem: all kernels now <43us each; K2's 15-tap vertical read
// (252 MB of L3 tap traffic, XCD-striding kills L2 reuse) is the fat target
// -> register rolling-sum band kernel, 2 tap loads/row, no LDS, no barriers.
// Shapes fixed by the reference: x [16,512,512,3] fp32 NHWC.

#define BATCH  16
#define HEIGHT 512
#define WIDTH  512
#define NPIX   (BATCH * HEIGHT * WIDTH)   // 4,194,304
#define RAD    7
#define KS     15
#define EPSV   0.01f

#define W_R 0.2989f
#define W_G 0.5870f
#define W_B 0.1140f

// ---------------- K1: fused luma + horizontal 15-tap + per-block partial sums ---------
// Block = 2 full rows (1024 px). x rows -> LDS (coalesced float4), luma into a
// zero-padded LDS row buffer, 15-tap hblur from LDS (stride-1 reads = conflict
// free), per-block sums to partials[bid] (NO contended atomics).
__global__ __launch_bounds__(256) void k_luma_hblur(const float* __restrict__ x,
                                                    float* __restrict__ tmp,
                                                    float2* __restrict__ partials) {
    __shared__ float sx[3072];
    __shared__ float sl[2][528];            // 7 zero pad each side
    __shared__ float redG[4], redI[4];
    int t = threadIdx.x;

    if (t < 7) {                            // zero the halo pads once
        sl[0][t] = 0.f; sl[1][t] = 0.f;
        sl[0][519 + t] = 0.f; sl[1][519 + t] = 0.f;
    }

    size_t base4 = (size_t)blockIdx.x * 768;        // float4 units into x
    const float4* xv = (const float4*)x;
    float4* s4 = (float4*)sx;
#pragma unroll
    for (int i = 0; i < 3; i++)
        s4[i * 256 + t] = xv[base4 + i * 256 + t];
    __syncthreads();

    // luma for pixels p = t + 256*i
    float sG = 0.f, sI = 0.f;
#pragma unroll
    for (int i = 0; i < 4; i++) {
        int p  = t + (i << 8);
        int lr = p >> 9;
        int c  = p & (WIDTH - 1);
        float r  = (sx[3 * p + 0] + 1.f) * 0.5f;
        float gg = (sx[3 * p + 1] + 1.f) * 0.5f;
        float bb = (sx[3 * p + 2] + 1.f) * 0.5f;
        float l  = W_R * r + W_G * gg + W_B * bb;
        sl[lr][RAD + c] = l;
        sG += l;
        sI += r + gg + bb;
    }

#pragma unroll
    for (int off = 32; off > 0; off >>= 1) {
        sG += __shfl_down(sG, off, 64);
        sI += __shfl_down(sI, off, 64);
    }
    int lane = t & 63, wave = t >> 6;
    if (lane == 0) { redG[wave] = sG; redI[wave] = sI; }
    __syncthreads();                        // covers sl + redG/redI

    if (t == 0)
        partials[blockIdx.x] = make_float2(redG[0] + redG[1] + redG[2] + redG[3],
                                           redI[0] + redI[1] + redI[2] + redI[3]);

    // hblur: 15 unconditional LDS taps per pixel, coalesced dword stores
    int row_g = blockIdx.x * 2;
#pragma unroll
    for (int i = 0; i < 4; i++) {
        int p  = t + (i << 8);
        int lr = p >> 9;
        int c  = p & (WIDTH - 1);
        float sum = 0.f;
#pragma unroll
        for (int d = 0; d < KS; d++) sum += sl[lr][c + d];
        tmp[(size_t)(row_g + lr) * WIDTH + c] = sum;   // 1/225 folded into K2
    }
}

// ---------------- K1.5: reduce 4096 partials -> offset (1 block) ----------------
__global__ __launch_bounds__(256) void k_reduce(const float2* __restrict__ partials,
                                                float* __restrict__ sums) {
    int t = threadIdx.x;
    float sG = 0.f, sI = 0.f;
    for (int i = t; i < 4096; i += 256) {
        float2 v = partials[i];
        sG += v.x; sI += v.y;
    }
#pragma unroll
    for (int off = 32; off > 0; off >>= 1) {
        sG += __shfl_down(sG, off, 64);
        sI += __shfl_down(sI, off, 64);
    }
    __shared__ float rG[4], rI[4];
    int lane = t & 63, wave = t >> 6;
    if (lane == 0) { rG[wave] = sG; rI[wave] = sI; }
    __syncthreads();
    if (t == 0) {
        float SG = rG[0] + rG[1] + rG[2] + rG[3];
        float SI = rI[0] + rI[1] + rI[2] + rI[3];
        float meanG = SG * (1.f / (float)NPIX);
        float meanI = SI * (1.f / (3.f * (float)NPIX));
        sums[0] = meanI - meanG;            // the offset, directly
    }
}

// ---------------- K2: rolling-sum vertical blur + fused combine (no LDS) --------------
// Block = 128 threads = full width (thread t owns float4 column t = pixels
// 4t..4t+3) x T=16 rows of one image. Rolling window: init with <=15 tap rows,
// then 2 tap loads per output row. addv->RGB mapping is static per thread
// (pixels 4t..4t+3 <-> out float4s 3t..3t+2), so combine is pure registers.
#define TROWS 16
__global__ __launch_bounds__(128) void k_vblur_combine(const float* __restrict__ tmp,
                                                       const float* __restrict__ x,
                                                       float* __restrict__ out,
                                                       const float* __restrict__ sums) {
    int t    = threadIdx.x;                 // float4 column 0..127
    int band = blockIdx.x & (HEIGHT / TROWS - 1);
    int b    = blockIdx.x >> 5;             // image (512/16 = 32 bands)
    int y0   = band * TROWS;
    float offset = sums[0];
    const float nrm   = 1.f / (float)(KS * KS);
    const float scale = 1.f - EPSV;

    int col = t << 2;
    float c0 = (float)(min(col + 0, RAD) + 1 + min(WIDTH - 1 - col, RAD));
    float c1 = (float)(min(col + 1, RAD) + 1 + min(WIDTH - 2 - col, RAD));
    float c2 = (float)(min(col + 2, RAD) + 1 + min(WIDTH - 3 - col, RAD));
    float c3 = (float)(min(col + 3, RAD) + 1 + min(WIDTH - 4 - col, RAD));

    const float4* tv = (const float4*)tmp + (size_t)b * HEIGHT * (WIDTH / 4) + t;

    // init window = rows [max(0,y0-7), y0+7]   (y0+7 <= 511 always)
    float s0 = 0.f, s1 = 0.f, s2 = 0.f, s3 = 0.f;
    int rlo = y0 - RAD < 0 ? 0 : y0 - RAD;
    for (int r = rlo; r <= y0 + RAD; ++r) {
        float4 v = tv[(size_t)r * (WIDTH / 4)];
        s0 += v.x; s1 += v.y; s2 += v.z; s3 += v.w;
    }

    const float4* xv = (const float4*)x   + (size_t)b * HEIGHT * 384;
    float4*       ov = (float4*)out       + (size_t)b * HEIGHT * 384;

#pragma unroll
    for (int i = 0; i < TROWS; ++i) {
        int y = y0 + i;
        float cy = (float)(min(y, RAD) + 1 + min(HEIGHT - 1 - y, RAD));
        float k  = offset * cy;
        float a0 = EPSV * (2.f * (s0 + k * c0) * nrm - 1.f);
        float a1 = EPSV * (2.f * (s1 + k * c1) * nrm - 1.f);
        float a2 = EPSV * (2.f * (s2 + k * c2) * nrm - 1.f);
        float a3 = EPSV * (2.f * (s3 + k * c3) * nrm - 1.f);

        size_t rb = (size_t)y * 384 + 3 * t;
        float4 x0 = xv[rb + 0];
        float4 x1 = xv[rb + 1];
        float4 x2 = xv[rb + 2];
        float4 o0, o1, o2;
        o0.x = x0.x * scale + a0; o0.y = x0.y * scale + a0;
        o0.z = x0.z * scale + a0; o0.w = x0.w * scale + a1;
        o1.x = x1.x * scale + a1; o1.y = x1.y * scale + a1;
        o1.z = x1.z * scale + a2; o1.w = x1.w * scale + a2;
        o2.x = x2.x * scale + a2; o2.y = x2.y * scale + a3;
        o2.z = x2.z * scale + a3; o2.w = x2.w * scale + a3;
        ov[rb + 0] = o0;
        ov[rb + 1] = o1;
        ov[rb + 2] = o2;

        // window(y+1) = window(y) + tmp[y+8] - tmp[y-7]   (wave-uniform branches)
        if (y + RAD + 1 < HEIGHT) {
            float4 v = tv[(size_t)(y + RAD + 1) * (WIDTH / 4)];
            s0 += v.x; s1 += v.y; s2 += v.z; s3 += v.w;
        }
        if (y - RAD >= 0) {
            float4 v = tv[(size_t)(y - RAD) * (WIDTH / 4)];
            s0 -= v.x; s1 -= v.y; s2 -= v.z; s3 -= v.w;
        }
    }
}

extern "C" void kernel_launch(void* const* d_in, const int* in_sizes, int n_in,
                              void* d_out, int out_size, void* d_ws, size_t ws_size,
                              hipStream_t stream) {
    const float* x   = (const float*)d_in[0];
    float*       out = (float*)d_out;

    // ws layout: [0,256): sums | [256, 256+32K): partials (4096 float2) | tmp: NPIX floats
    float*  sums     = (float*)d_ws;
    float2* partials = (float2*)((char*)d_ws + 256);
    float*  tmp      = (float*)((char*)d_ws + 256 + 4096 * sizeof(float2));

    k_luma_hblur<<<BATCH * HEIGHT / 2, 256, 0, stream>>>(x, tmp, partials);
    k_reduce<<<1, 256, 0, stream>>>(partials, sums);
    k_vblur_combine<<<BATCH * (HEIGHT / TROWS), 128, 0, stream>>>(tmp, x, out, sums);
}

// Round 8
// 111.951 us; speedup vs baseline: 2.1653x; 1.0639x over previous
//
#include <hip/hip_runtime.h>

// GuidedFilterLayer: out = x*(1-eps) + eps*(2*smoothed - 1)
//   g        = luma((x+1)/2)
//   smoothed = boxblur15_zeropad(g + offset),  offset = mean(inputs)-mean(g)
// Linearity: boxblur_zeropad(g + c) = boxblur_zeropad(g) + c*cx(x)*cy(y)/225,
// so offset only enters the final combine. History: R3 removed 8192 contended
// atomics (232->128us); R6 rolling-sum vblur (128->119us); R7 profile showed
// ~65-70us of dur_us is the harness's own poison/restore traffic (268MB fill
// at 43us etc.), kernels ~50us vs ~40us ideal. This round: fp16 tmp (halves
// tmp traffic; error ~5e-6 << 0.02 threshold), rolling hblur (21 LDS taps per
// 4 px instead of 60), k_reduce folded into K2 (each block re-reduces 2048
// partials from L2/L3), TROWS=8 for 8 waves/CU latency hiding in K2.
// Shapes fixed by the reference: x [16,512,512,3] fp32 NHWC.

#define BATCH  16
#define HEIGHT 512
#define WIDTH  512
#define NPIX   (BATCH * HEIGHT * WIDTH)   // 4,194,304
#define RAD    7
#define KS     15
#define EPSV   0.01f

#define W_R 0.2989f
#define W_G 0.5870f
#define W_B 0.1140f

typedef _Float16 h4 __attribute__((ext_vector_type(4)));

// ---------------- K1: luma + rolling horizontal 15-tap + per-block partials -----------
// Block = 2 rows (1024 px), 256 threads; thread t owns pixels 4t..4t+3
// (= float4s 3t..3t+2, directly loaded — consecutive lanes cover consecutive
// memory, no LDS staging). Luma into an aligned-pad LDS row ([8 pad][512][8
// pad] so the float4 write lands 16B-aligned), one barrier, then rolling
// 15-tap: 15 init + 6 update LDS reads per 4 outputs. tmp stored as fp16x4.
__global__ __launch_bounds__(256) void k_luma_hblur(const float* __restrict__ x,
                                                    h4* __restrict__ tmp,
                                                    float2* __restrict__ partials) {
    __shared__ float sl[2][528];            // [8 zero][512 luma][8 zero]
    __shared__ float redG[4], redI[4];
    int t  = threadIdx.x;
    int lr = t >> 7;                        // local row 0/1
    int tc = t & 127;                       // float4-column within row
    int c0 = tc << 2;                       // first pixel column

    if (t < 8) {                            // zero halos once (pre-barrier)
        sl[0][t] = 0.f; sl[1][t] = 0.f;
        sl[0][520 + t] = 0.f; sl[1][520 + t] = 0.f;
    }

    const float4* xv = (const float4*)x;
    size_t tb = (size_t)blockIdx.x * 768 + 3 * t;
    float4 A = xv[tb + 0];
    float4 B = xv[tb + 1];
    float4 C = xv[tb + 2];

    float r0 = (A.x + 1.f) * 0.5f, g0 = (A.y + 1.f) * 0.5f, b0 = (A.z + 1.f) * 0.5f;
    float r1 = (A.w + 1.f) * 0.5f, g1 = (B.x + 1.f) * 0.5f, b1 = (B.y + 1.f) * 0.5f;
    float r2 = (B.z + 1.f) * 0.5f, g2 = (B.w + 1.f) * 0.5f, b2 = (C.x + 1.f) * 0.5f;
    float r3 = (C.y + 1.f) * 0.5f, g3 = (C.z + 1.f) * 0.5f, b3 = (C.w + 1.f) * 0.5f;

    float l0 = W_R * r0 + W_G * g0 + W_B * b0;
    float l1 = W_R * r1 + W_G * g1 + W_B * b1;
    float l2 = W_R * r2 + W_G * g2 + W_B * b2;
    float l3 = W_R * r3 + W_G * g3 + W_B * b3;

    *(float4*)&sl[lr][8 + c0] = make_float4(l0, l1, l2, l3);   // 16B-aligned b128

    float sG = l0 + l1 + l2 + l3;
    float sI = r0 + g0 + b0 + r1 + g1 + b1 + r2 + g2 + b2 + r3 + g3 + b3;
#pragma unroll
    for (int off = 32; off > 0; off >>= 1) {
        sG += __shfl_down(sG, off, 64);
        sI += __shfl_down(sI, off, 64);
    }
    int lane = t & 63, wave = t >> 6;
    if (lane == 0) { redG[wave] = sG; redI[wave] = sI; }
    __syncthreads();                        // covers sl + redG/redI

    if (t == 0)
        partials[blockIdx.x] = make_float2(redG[0] + redG[1] + redG[2] + redG[3],
                                           redI[0] + redI[1] + redI[2] + redI[3]);

    // rolling hblur: window for col c = slots [c+1 .. c+15]
    const float* row = sl[lr];
    float s = 0.f;
#pragma unroll
    for (int d = 1; d <= 15; d++) s += row[c0 + d];
    float o0 = s;
    s += row[c0 + 16] - row[c0 + 1];  float o1 = s;
    s += row[c0 + 17] - row[c0 + 2];  float o2 = s;
    s += row[c0 + 18] - row[c0 + 3];  float o3 = s;

    h4 hv; hv.x = (_Float16)o0; hv.y = (_Float16)o1; hv.z = (_Float16)o2; hv.w = (_Float16)o3;
    tmp[(size_t)(blockIdx.x * 2 + lr) * 128 + tc] = hv;   // 1/225 folded into K2
}

// ---------------- K2: inline offset-reduce + rolling vblur + fused combine ------------
// Block = 128 threads (thread t owns float4 column t) x TROWS rows of one
// image; 1024 blocks = 8 waves/CU. First re-reduce the 2048 partials (16KB,
// L2/L3-resident; stream order makes K1's writes visible), then vertical
// rolling sum with 2 fp16x4 tap loads per row; combine is pure registers.
#define TROWS 8
__global__ __launch_bounds__(128) void k_vblur_combine(const h4* __restrict__ tmp,
                                                       const float* __restrict__ x,
                                                       float* __restrict__ out,
                                                       const float2* __restrict__ partials) {
    __shared__ float rr[4];
    int t = threadIdx.x;

    // ---- offset = mean(inputs) - mean(g), reduced per-block ----
    float sG = 0.f, sI = 0.f;
#pragma unroll
    for (int i = 0; i < 16; i++) {
        float2 v = partials[t + (i << 7)];
        sG += v.x; sI += v.y;
    }
#pragma unroll
    for (int off = 32; off > 0; off >>= 1) {
        sG += __shfl_down(sG, off, 64);
        sI += __shfl_down(sI, off, 64);
    }
    int lane = t & 63, wave = t >> 6;
    if (lane == 0) { rr[wave] = sG; rr[2 + wave] = sI; }
    __syncthreads();
    float offset = (rr[2] + rr[3]) * (1.f / (3.f * (float)NPIX))
                 - (rr[0] + rr[1]) * (1.f / (float)NPIX);

    int band = blockIdx.x & (HEIGHT / TROWS - 1);
    int b    = blockIdx.x >> 6;             // 512/8 = 64 bands per image
    int y0   = band * TROWS;
    const float nrm   = 1.f / (float)(KS * KS);
    const float scale = 1.f - EPSV;

    int col = t << 2;
    float c0 = (float)(min(col + 0, RAD) + 1 + min(WIDTH - 1 - col, RAD));
    float c1 = (float)(min(col + 1, RAD) + 1 + min(WIDTH - 2 - col, RAD));
    float c2 = (float)(min(col + 2, RAD) + 1 + min(WIDTH - 3 - col, RAD));
    float c3 = (float)(min(col + 3, RAD) + 1 + min(WIDTH - 4 - col, RAD));

    const h4* tv = tmp + (size_t)b * HEIGHT * 128 + t;

    // init window = rows [max(0,y0-7), y0+7]
    float s0 = 0.f, s1 = 0.f, s2 = 0.f, s3 = 0.f;
    int rlo = y0 - RAD < 0 ? 0 : y0 - RAD;
    for (int r = rlo; r <= y0 + RAD; ++r) {
        h4 v = tv[(size_t)r * 128];
        s0 += (float)v.x; s1 += (float)v.y; s2 += (float)v.z; s3 += (float)v.w;
    }

    const float4* xv = (const float4*)x + (size_t)b * HEIGHT * 384;
    float4*       ov = (float4*)out     + (size_t)b * HEIGHT * 384;

#pragma unroll
    for (int i = 0; i < TROWS; ++i) {
        int y = y0 + i;
        float cy = (float)(min(y, RAD) + 1 + min(HEIGHT - 1 - y, RAD));
        float k  = offset * cy;
        float a0 = EPSV * (2.f * (s0 + k * c0) * nrm - 1.f);
        float a1 = EPSV * (2.f * (s1 + k * c1) * nrm - 1.f);
        float a2 = EPSV * (2.f * (s2 + k * c2) * nrm - 1.f);
        float a3 = EPSV * (2.f * (s3 + k * c3) * nrm - 1.f);

        size_t rb = (size_t)y * 384 + 3 * t;
        float4 x0 = xv[rb + 0];
        float4 x1 = xv[rb + 1];
        float4 x2 = xv[rb + 2];
        float4 o0, o1, o2;
        o0.x = x0.x * scale + a0; o0.y = x0.y * scale + a0;
        o0.z = x0.z * scale + a0; o0.w = x0.w * scale + a1;
        o1.x = x1.x * scale + a1; o1.y = x1.y * scale + a1;
        o1.z = x1.z * scale + a2; o1.w = x1.w * scale + a2;
        o2.x = x2.x * scale + a2; o2.y = x2.y * scale + a3;
        o2.z = x2.z * scale + a3; o2.w = x2.w * scale + a3;
        ov[rb + 0] = o0;
        ov[rb + 1] = o1;
        ov[rb + 2] = o2;

        if (y + RAD + 1 < HEIGHT) {         // wave-uniform
            h4 v = tv[(size_t)(y + RAD + 1) * 128];
            s0 += (float)v.x; s1 += (float)v.y; s2 += (float)v.z; s3 += (float)v.w;
        }
        if (y - RAD >= 0) {
            h4 v = tv[(size_t)(y - RAD) * 128];
            s0 -= (float)v.x; s1 -= (float)v.y; s2 -= (float)v.z; s3 -= (float)v.w;
        }
    }
}

extern "C" void kernel_launch(void* const* d_in, const int* in_sizes, int n_in,
                              void* d_out, int out_size, void* d_ws, size_t ws_size,
                              hipStream_t stream) {
    const float* x   = (const float*)d_in[0];
    float*       out = (float*)d_out;

    // ws layout: [0, 16K): partials (2048 float2) | [32K, 32K+8.4M): tmp fp16
    float2* partials = (float2*)d_ws;
    h4*     tmp      = (h4*)((char*)d_ws + 32768);

    k_luma_hblur<<<BATCH * HEIGHT / 2, 256, 0, stream>>>(x, tmp, partials);
    k_vblur_combine<<<BATCH * (HEIGHT / TROWS), 128, 0, stream>>>(tmp, x, out, partials);
}